// Round 1
// baseline (4528.723 us; speedup 1.0000x reference)
//
#include <hip/hip_runtime.h>

#define IN_DIM  128
#define HID_DIM 128
#define OUT_DIM 64

// ---------- degree / normalization ----------
__global__ void init_deg(float* deg, int N) {
    int i = blockIdx.x * blockDim.x + threadIdx.x;
    if (i < N) deg[i] = 1.0f;  // self loop contributes 1
}

__global__ void count_deg(const int* __restrict__ dst, int E, float* deg) {
    int e = blockIdx.x * blockDim.x + threadIdx.x;
    if (e < E) atomicAdd(&deg[dst[e]], 1.0f);
}

__global__ void make_dinv(float* deg, int N) {
    int i = blockIdx.x * blockDim.x + threadIdx.x;
    if (i < N) deg[i] = 1.0f / sqrtf(deg[i]);  // deg >= 1 always (self loops)
}

// ---------- GEMM1: h1[N,128] = x[N,128] @ W1[128,128] ----------
// block = 128 threads (one per output column), ROWS rows per block.
template<int ROWS>
__global__ void gemm_x_w1(const float* __restrict__ x, const float* __restrict__ W,
                          float* __restrict__ h, int N) {
    __shared__ float xs[ROWS][IN_DIM];
    const int row0 = blockIdx.x * ROWS;
    const int tid  = threadIdx.x;  // 0..127 = output column j
    #pragma unroll
    for (int r = 0; r < ROWS; ++r) {
        int row = row0 + r;
        xs[r][tid] = (row < N) ? x[(long long)row * IN_DIM + tid] : 0.0f;
    }
    __syncthreads();
    float acc[ROWS];
    #pragma unroll
    for (int r = 0; r < ROWS; ++r) acc[r] = 0.0f;
    for (int k = 0; k < IN_DIM; ++k) {
        float w = W[k * HID_DIM + tid];   // coalesced; W1 is 64KB, L1/L2 resident
        #pragma unroll
        for (int r = 0; r < ROWS; ++r) acc[r] += xs[r][k] * w;  // LDS broadcast
    }
    #pragma unroll
    for (int r = 0; r < ROWS; ++r) {
        int row = row0 + r;
        if (row < N) h[(long long)row * HID_DIM + tid] = acc[r];
    }
}

// ---------- GEMM2: h2[N,64] = relu(agg[N,128] + b1) @ W2[128,64] ----------
// block = 256 threads = 4 row-groups x 64 columns; 16 rows per block.
__global__ void gemm_h_w2(const float* __restrict__ agg, const float* __restrict__ b1,
                          const float* __restrict__ W2, float* __restrict__ h2, int N) {
    __shared__ float xs[16][HID_DIM];
    const int row0 = blockIdx.x * 16;
    const int tid  = threadIdx.x;
    for (int i = tid; i < 16 * HID_DIM; i += 256) {
        int r = i >> 7, k = i & 127;
        int row = row0 + r;
        float v = (row < N) ? agg[(long long)row * HID_DIM + k] + b1[k] : 0.0f;
        xs[r][k] = fmaxf(v, 0.0f);   // fused bias + relu
    }
    __syncthreads();
    const int j  = tid & 63;
    const int r0 = tid >> 6;  // 0..3
    float acc[4] = {0.f, 0.f, 0.f, 0.f};
    for (int k = 0; k < HID_DIM; ++k) {
        float w = W2[k * OUT_DIM + j];  // coalesced across the wave
        #pragma unroll
        for (int q = 0; q < 4; ++q) acc[q] += xs[r0 + q * 4][k] * w;  // LDS broadcast
    }
    #pragma unroll
    for (int q = 0; q < 4; ++q) {
        int row = row0 + r0 + q * 4;
        if (row < N) h2[(long long)row * OUT_DIM + j] = acc[q];
    }
}

// ---------- out init: out[i][j] = b2[j] ----------
__global__ void init_out_b2(float* out, const float* __restrict__ b2, int total) {
    int t = blockIdx.x * blockDim.x + threadIdx.x;
    if (t < total) out[t] = b2[t & (OUT_DIM - 1)];
}

// ---------- edge scatter: agg[dst] += h[src] * norm, over E real edges + N self loops ----------
// One thread per (edge, 4 features). Threads of one edge are contiguous -> coalesced
// float4 reads of h[src]; 4 scalar f32 atomics per thread to agg[dst].
template<int D>
__global__ void scatter_edges(const float* __restrict__ h, const int* __restrict__ src,
                              const int* __restrict__ dst, const float* __restrict__ dinv,
                              int E, int N, float* agg) {
    const int TPE = D / 4;                  // threads per edge
    int t = blockIdx.x * blockDim.x + threadIdx.x;
    int total = (E + N) * TPE;              // 54.4M (D=128) / 27.2M (D=64): fits int
    if (t >= total) return;
    int e = t / TPE;                        // TPE is power of 2 -> shift
    int f = (t & (TPE - 1)) * 4;
    int s, d; float nrm;
    if (e < E) {
        s = src[e]; d = dst[e];
        nrm = dinv[s] * dinv[d];
    } else {
        s = d = e - E;                      // self loop
        float di = dinv[s];
        nrm = di * di;
    }
    const float4 v = *(const float4*)(h + (long long)s * D + f);
    float* o = agg + (long long)d * D + f;
    atomicAdd(o + 0, v.x * nrm);
    atomicAdd(o + 1, v.y * nrm);
    atomicAdd(o + 2, v.z * nrm);
    atomicAdd(o + 3, v.w * nrm);
}

extern "C" void kernel_launch(void* const* d_in, const int* in_sizes, int n_in,
                              void* d_out, int out_size, void* d_ws, size_t ws_size,
                              hipStream_t stream) {
    const float* x   = (const float*)d_in[0];
    const int*   ei  = (const int*)  d_in[1];
    const float* W1  = (const float*)d_in[2];
    const float* b1  = (const float*)d_in[3];
    const float* W2  = (const float*)d_in[4];
    const float* b2  = (const float*)d_in[5];
    float* out = (float*)d_out;

    const int N = in_sizes[0] / IN_DIM;     // 100000
    const int E = in_sizes[1] / 2;          // 1600000
    const int* src = ei;                    // edge_index[0]
    const int* dst = ei + E;                // edge_index[1]

    // workspace layout (floats): dinv[N] | bufA[N*128] (h1, then h2) | bufB[N*128] (agg1)
    float* dinv = (float*)d_ws;
    float* bufA = dinv + N;                 // offset 400000 B, 16B-aligned
    float* bufB = bufA + (long long)N * HID_DIM;
    float* h1   = bufA;
    float* agg1 = bufB;
    float* h2   = bufA;                     // reuse after agg1 is built

    const int B = 256;

    // 1) degrees -> dinv
    init_deg<<<(N + B - 1) / B, B, 0, stream>>>(dinv, N);
    count_deg<<<(E + B - 1) / B, B, 0, stream>>>(dst, E, dinv);
    make_dinv<<<(N + B - 1) / B, B, 0, stream>>>(dinv, N);

    // 2) h1 = x @ W1
    gemm_x_w1<8><<<(N + 7) / 8, 128, 0, stream>>>(x, W1, h1, N);

    // 3) agg1 = scatter(h1)
    hipMemsetAsync(agg1, 0, (size_t)N * HID_DIM * sizeof(float), stream);
    {
        int total = (E + N) * (HID_DIM / 4);
        scatter_edges<HID_DIM><<<(total + B - 1) / B, B, 0, stream>>>(
            h1, src, dst, dinv, E, N, agg1);
    }

    // 4) h2 = relu(agg1 + b1) @ W2
    gemm_h_w2<<<(N + 15) / 16, 256, 0, stream>>>(agg1, b1, W2, h2, N);

    // 5) out = b2 + scatter(h2)
    init_out_b2<<<(N * OUT_DIM + B - 1) / B, B, 0, stream>>>(out, b2, N * OUT_DIM);
    {
        int total = (E + N) * (OUT_DIM / 4);
        scatter_edges<OUT_DIM><<<(total + B - 1) / B, B, 0, stream>>>(
            h2, src, dst, dinv, E, N, out);
    }
}

// Round 2
// 660.771 us; speedup vs baseline: 6.8537x; 6.8537x over previous
//
#include <hip/hip_runtime.h>

#define IN_DIM  128
#define HID_DIM 128
#define OUT_DIM 64

// ---------------- degree count (int) ----------------
__global__ void count_deg(const int* __restrict__ dst, int E, int* __restrict__ cnt) {
    int e = blockIdx.x * blockDim.x + threadIdx.x;
    if (e < E) atomicAdd(&cnt[dst[e]], 1);
}

__global__ void make_dinv(const int* __restrict__ cnt, float* __restrict__ dinv, int N) {
    int i = blockIdx.x * blockDim.x + threadIdx.x;
    if (i < N) dinv[i] = rsqrtf((float)(cnt[i] + 1));  // +1 self loop
}

// ---------------- single-block exclusive scan over cnt[N] ----------------
// 1024 threads, 4 elements/thread/iteration (chunk = 4096).
__global__ void scan_deg(const int* __restrict__ cnt, int* __restrict__ row_start,
                         int* __restrict__ cursor, int N) {
    __shared__ int wsum[16];
    __shared__ int chunk_total;
    const int t = threadIdx.x;
    const int lane = t & 63;
    const int wave = t >> 6;
    int running = 0;
    for (int base = 0; base < N; base += 4096) {
        int idx = base + t * 4;
        int v0 = (idx     < N) ? cnt[idx]     : 0;
        int v1 = (idx + 1 < N) ? cnt[idx + 1] : 0;
        int v2 = (idx + 2 < N) ? cnt[idx + 2] : 0;
        int v3 = (idx + 3 < N) ? cnt[idx + 3] : 0;
        int s = v0 + v1 + v2 + v3;
        // wave-level inclusive scan of s
        int incl = s;
        #pragma unroll
        for (int off = 1; off < 64; off <<= 1) {
            int u = __shfl_up(incl, off);
            if (lane >= off) incl += u;
        }
        if (lane == 63) wsum[wave] = incl;
        __syncthreads();
        if (t < 16) {
            int ws = wsum[t];
            #pragma unroll
            for (int off = 1; off < 16; off <<= 1) {
                int u = __shfl_up(ws, off);
                if (t >= off) ws += u;
            }
            wsum[t] = ws;                    // inclusive wave sums
            if (t == 15) chunk_total = ws;
        }
        __syncthreads();
        int wave_off = (wave == 0) ? 0 : wsum[wave - 1];
        int excl = running + wave_off + (incl - s);
        if (idx     < N) { row_start[idx]     = excl;            cursor[idx]     = excl; }
        if (idx + 1 < N) { int e1 = excl + v0; row_start[idx+1] = e1; cursor[idx+1] = e1; }
        if (idx + 2 < N) { int e2 = excl + v0 + v1; row_start[idx+2] = e2; cursor[idx+2] = e2; }
        if (idx + 3 < N) { int e3 = excl + v0 + v1 + v2; row_start[idx+3] = e3; cursor[idx+3] = e3; }
        running += chunk_total;
        __syncthreads();                     // wsum/chunk_total reused next iter
    }
}

// ---------------- fill CSR: srcSorted bucketed by dst ----------------
// After this kernel cursor[i] == row_end[i].
__global__ void fill_csr(const int* __restrict__ src, const int* __restrict__ dst, int E,
                         int* __restrict__ cursor, int* __restrict__ srcSorted) {
    int e = blockIdx.x * blockDim.x + threadIdx.x;
    if (e < E) {
        int d = dst[e];
        int pos = atomicAdd(&cursor[d], 1);
        srcSorted[pos] = src[e];
    }
}

// ---------------- GEMM1: h1[N,128] = x[N,128] @ W1[128,128] ----------------
template<int ROWS>
__global__ void gemm_x_w1(const float* __restrict__ x, const float* __restrict__ W,
                          float* __restrict__ h, int N) {
    __shared__ float xs[ROWS][IN_DIM];
    const int row0 = blockIdx.x * ROWS;
    const int tid  = threadIdx.x;  // 0..127 = output column j
    #pragma unroll
    for (int r = 0; r < ROWS; ++r) {
        int row = row0 + r;
        xs[r][tid] = (row < N) ? x[(long long)row * IN_DIM + tid] : 0.0f;
    }
    __syncthreads();
    float acc[ROWS];
    #pragma unroll
    for (int r = 0; r < ROWS; ++r) acc[r] = 0.0f;
    for (int k = 0; k < IN_DIM; ++k) {
        float w = W[k * HID_DIM + tid];
        #pragma unroll
        for (int r = 0; r < ROWS; ++r) acc[r] += xs[r][k] * w;
    }
    #pragma unroll
    for (int r = 0; r < ROWS; ++r) {
        int row = row0 + r;
        if (row < N) h[(long long)row * HID_DIM + tid] = acc[r];
    }
}

// ---------------- GEMM2: h2[N,64] = relu(agg[N,128] + b1) @ W2[128,64] ----------------
__global__ void gemm_h_w2(const float* __restrict__ agg, const float* __restrict__ b1,
                          const float* __restrict__ W2, float* __restrict__ h2, int N) {
    __shared__ float xs[16][HID_DIM];
    const int row0 = blockIdx.x * 16;
    const int tid  = threadIdx.x;
    for (int i = tid; i < 16 * HID_DIM; i += 256) {
        int r = i >> 7, k = i & 127;
        int row = row0 + r;
        float v = (row < N) ? agg[(long long)row * HID_DIM + k] + b1[k] : 0.0f;
        xs[r][k] = fmaxf(v, 0.0f);   // fused bias + relu
    }
    __syncthreads();
    const int j  = tid & 63;
    const int r0 = tid >> 6;  // 0..3
    float acc[4] = {0.f, 0.f, 0.f, 0.f};
    for (int k = 0; k < HID_DIM; ++k) {
        float w = W2[k * OUT_DIM + j];
        #pragma unroll
        for (int q = 0; q < 4; ++q) acc[q] += xs[r0 + q * 4][k] * w;
    }
    #pragma unroll
    for (int q = 0; q < 4; ++q) {
        int row = row0 + r0 + q * 4;
        if (row < N) h2[(long long)row * OUT_DIM + j] = acc[q];
    }
}

// ---------------- gather aggregation (no atomics) ----------------
// out[i] = (bias) + dinv[i]^2 * h[i] + sum_{e in CSR[i]} dinv[src]*dinv[i] * h[src]
// TPN = D/4 threads per node; float4 per thread.
template<int D, int NPB>
__global__ void gather_nodes(const float* __restrict__ h, const int* __restrict__ srcSorted,
                             const int* __restrict__ row_start, const int* __restrict__ row_end,
                             const float* __restrict__ dinv, const float* __restrict__ bias,
                             int N, float* __restrict__ out) {
    const int TPN = D / 4;
    const int t = threadIdx.x;
    const int node = blockIdx.x * NPB + t / TPN;
    if (node >= N) return;
    const int f = (t & (TPN - 1)) * 4;
    const float dd = dinv[node];

    const float4 self = *(const float4*)(h + (long long)node * D + f);
    float sn = dd * dd;
    float4 acc;
    acc.x = self.x * sn; acc.y = self.y * sn; acc.z = self.z * sn; acc.w = self.w * sn;
    if (bias) {
        acc.x += bias[f]; acc.y += bias[f + 1]; acc.z += bias[f + 2]; acc.w += bias[f + 3];
    }

    int e   = row_start[node];
    int end = row_end[node];
    // 2x unrolled for ILP on the dependent load chains
    for (; e + 1 < end; e += 2) {
        int s0 = srcSorted[e], s1 = srcSorted[e + 1];
        float n0 = dinv[s0] * dd, n1 = dinv[s1] * dd;
        const float4 v0 = *(const float4*)(h + (long long)s0 * D + f);
        const float4 v1 = *(const float4*)(h + (long long)s1 * D + f);
        acc.x += v0.x * n0 + v1.x * n1;
        acc.y += v0.y * n0 + v1.y * n1;
        acc.z += v0.z * n0 + v1.z * n1;
        acc.w += v0.w * n0 + v1.w * n1;
    }
    if (e < end) {
        int s0 = srcSorted[e];
        float n0 = dinv[s0] * dd;
        const float4 v0 = *(const float4*)(h + (long long)s0 * D + f);
        acc.x += v0.x * n0; acc.y += v0.y * n0; acc.z += v0.z * n0; acc.w += v0.w * n0;
    }
    *(float4*)(out + (long long)node * D + f) = acc;
}

extern "C" void kernel_launch(void* const* d_in, const int* in_sizes, int n_in,
                              void* d_out, int out_size, void* d_ws, size_t ws_size,
                              hipStream_t stream) {
    const float* x   = (const float*)d_in[0];
    const int*   ei  = (const int*)  d_in[1];
    const float* W1  = (const float*)d_in[2];
    const float* b1  = (const float*)d_in[3];
    const float* W2  = (const float*)d_in[4];
    const float* b2  = (const float*)d_in[5];
    float* out = (float*)d_out;

    const int N = in_sizes[0] / IN_DIM;     // 100000
    const int E = in_sizes[1] / 2;          // 1600000
    const int* src = ei;                    // edge_index[0]
    const int* dst = ei + E;                // edge_index[1]

    // workspace layout:
    // dinv[N] f32 | cnt[N] i32 | row_start[N] i32 | cursor[N] i32 | srcSorted[E] i32
    // | bufA[N*128] f32 | bufB[N*128] f32
    float* dinv      = (float*)d_ws;
    int*   cnt       = (int*)(dinv + N);
    int*   row_start = cnt + N;
    int*   cursor    = row_start + N;
    int*   srcSorted = cursor + N;
    float* bufA      = (float*)(srcSorted + E);
    float* bufB      = bufA + (long long)N * HID_DIM;
    float* h1   = bufA;
    float* agg1 = bufB;
    float* h2   = bufA;                     // reuse after agg1 built

    const int B = 256;

    // 1) CSR build + dinv
    hipMemsetAsync(cnt, 0, (size_t)N * sizeof(int), stream);
    count_deg<<<(E + B - 1) / B, B, 0, stream>>>(dst, E, cnt);
    make_dinv<<<(N + B - 1) / B, B, 0, stream>>>(cnt, dinv, N);
    scan_deg<<<1, 1024, 0, stream>>>(cnt, row_start, cursor, N);
    fill_csr<<<(E + B - 1) / B, B, 0, stream>>>(src, dst, E, cursor, srcSorted);
    // after fill: cursor[i] == row_end[i]

    // 2) h1 = x @ W1
    gemm_x_w1<8><<<(N + 7) / 8, 128, 0, stream>>>(x, W1, h1, N);

    // 3) agg1 = gather(h1)   (no bias; b1 fused into gemm2)
    gather_nodes<HID_DIM, 8><<<(N + 7) / 8, 256, 0, stream>>>(
        h1, srcSorted, row_start, cursor, dinv, nullptr, N, agg1);

    // 4) h2 = relu(agg1 + b1) @ W2
    gemm_h_w2<<<(N + 15) / 16, 256, 0, stream>>>(agg1, b1, W2, h2, N);

    // 5) out = b2 + gather(h2)
    gather_nodes<OUT_DIM, 16><<<(N + 15) / 16, 256, 0, stream>>>(
        h2, srcSorted, row_start, cursor, dinv, b2, N, out);
}

// Round 3
// 572.299 us; speedup vs baseline: 7.9132x; 1.1546x over previous
//
#include <hip/hip_runtime.h>

#define IN_DIM  128
#define HID_DIM 128
#define OUT_DIM 64

// ---------------- degree count + per-edge rank ----------------
__global__ void count_rank(const int* __restrict__ dst, int E,
                           int* __restrict__ cnt, int* __restrict__ rank) {
    int e = blockIdx.x * blockDim.x + threadIdx.x;
    if (e < E) rank[e] = atomicAdd(&cnt[dst[e]], 1);
}

__global__ void make_dinv(const int* __restrict__ cnt, float* __restrict__ dinv, int N) {
    int i = blockIdx.x * blockDim.x + threadIdx.x;
    if (i < N) dinv[i] = rsqrtf((float)(cnt[i] + 1));  // +1 self loop
}

// ---------------- 3-kernel scan over cnt[N] (chunk = 2048/block) ----------------
__global__ void scan_partial(const int* __restrict__ cnt, int* __restrict__ bsum, int N) {
    __shared__ int wsum[4];
    const int t = threadIdx.x;
    const int base = blockIdx.x * 2048 + t * 8;
    int s = 0;
    #pragma unroll
    for (int i = 0; i < 8; ++i) s += (base + i < N) ? cnt[base + i] : 0;
    // wave reduce
    #pragma unroll
    for (int off = 32; off > 0; off >>= 1) s += __shfl_down(s, off);
    const int lane = t & 63, w = t >> 6;
    if (lane == 0) wsum[w] = s;
    __syncthreads();
    if (t == 0) bsum[blockIdx.x] = wsum[0] + wsum[1] + wsum[2] + wsum[3];
}

__global__ void scan_partials(int* __restrict__ bsum, int S) {
    const int t = threadIdx.x;  // 64 threads, single wave
    int running = 0;
    for (int base = 0; base < S; base += 64) {
        int i = base + t;
        int v = (i < S) ? bsum[i] : 0;
        int incl = v;
        #pragma unroll
        for (int off = 1; off < 64; off <<= 1) {
            int u = __shfl_up(incl, off);
            if (t >= off) incl += u;
        }
        if (i < S) bsum[i] = running + incl - v;   // exclusive
        running += __shfl(incl, 63);
    }
}

__global__ void scan_write(const int* __restrict__ cnt, const int* __restrict__ bsum,
                           int* __restrict__ row_start, int N) {
    __shared__ int wsum[4];
    const int t = threadIdx.x;
    const int base = blockIdx.x * 2048 + t * 8;
    int v[8];
    #pragma unroll
    for (int i = 0; i < 8; ++i) v[i] = (base + i < N) ? cnt[base + i] : 0;
    int s = v[0] + v[1] + v[2] + v[3] + v[4] + v[5] + v[6] + v[7];
    const int lane = t & 63, w = t >> 6;
    int incl = s;
    #pragma unroll
    for (int off = 1; off < 64; off <<= 1) {
        int u = __shfl_up(incl, off);
        if (lane >= off) incl += u;
    }
    if (lane == 63) wsum[w] = incl;
    __syncthreads();
    int woff = 0;
    for (int i = 0; i < w; ++i) woff += wsum[i];
    int run = bsum[blockIdx.x] + woff + (incl - s);
    #pragma unroll
    for (int i = 0; i < 8; ++i) {
        if (base + i < N) row_start[base + i] = run;
        run += v[i];
    }
}

// ---------------- fill CSR (no atomics) ----------------
__global__ void fill_csr(const int* __restrict__ src, const int* __restrict__ dst,
                         const int* __restrict__ rank, const int* __restrict__ row_start,
                         int E, int* __restrict__ srcSorted) {
    int e = blockIdx.x * blockDim.x + threadIdx.x;
    if (e < E) srcSorted[row_start[dst[e]] + rank[e]] = src[e];
}

// ---------------- GEMM1: h1[N,128] = x[N,128] @ W1[128,128] ----------------
// block 128: c = tid&63 -> cols {c, c+64}; g = tid>>6 -> rows g*8..g*8+7; 16 rows/block
__global__ void gemm_x_w1(const float* __restrict__ x, const float* __restrict__ W,
                          float* __restrict__ h, int N) {
    __shared__ float xs[16][IN_DIM];
    const int row0 = blockIdx.x * 16;
    const int tid  = threadIdx.x;
    {
        const int base = tid * 16;
        if (row0 + 16 <= N) {
            const float* s = x + (long long)row0 * IN_DIM;
            #pragma unroll
            for (int i = 0; i < 4; ++i)
                *(float4*)(&xs[0][0] + base + i * 4) = *(const float4*)(s + base + i * 4);
        } else {
            #pragma unroll
            for (int i = 0; i < 16; ++i) {
                int idx = base + i, r = idx >> 7, col = idx & 127;
                (&xs[0][0])[idx] = (row0 + r < N)
                    ? x[(long long)(row0 + r) * IN_DIM + col] : 0.0f;
            }
        }
    }
    __syncthreads();
    const int c = tid & 63;
    const int g = tid >> 6;
    float acc0[8] = {0,0,0,0,0,0,0,0};
    float acc1[8] = {0,0,0,0,0,0,0,0};
    const float* Wc = W + c;
    for (int k = 0; k < IN_DIM; k += 4) {
        const float wa0 = Wc[(k+0)*HID_DIM],      wa1 = Wc[(k+1)*HID_DIM];
        const float wa2 = Wc[(k+2)*HID_DIM],      wa3 = Wc[(k+3)*HID_DIM];
        const float wb0 = Wc[(k+0)*HID_DIM + 64], wb1 = Wc[(k+1)*HID_DIM + 64];
        const float wb2 = Wc[(k+2)*HID_DIM + 64], wb3 = Wc[(k+3)*HID_DIM + 64];
        #pragma unroll
        for (int r = 0; r < 8; ++r) {
            const float4 xv = *(const float4*)(&xs[g * 8 + r][k]);
            acc0[r] += xv.x * wa0 + xv.y * wa1 + xv.z * wa2 + xv.w * wa3;
            acc1[r] += xv.x * wb0 + xv.y * wb1 + xv.z * wb2 + xv.w * wb3;
        }
    }
    #pragma unroll
    for (int r = 0; r < 8; ++r) {
        int row = row0 + g * 8 + r;
        if (row < N) {
            h[(long long)row * HID_DIM + c]      = acc0[r];
            h[(long long)row * HID_DIM + c + 64] = acc1[r];
        }
    }
}

// ---------------- GEMM2: h2[N,64] = relu(agg + b1) @ W2[128,64] ----------------
// block 128: c = tid&31 -> cols {c, c+32}; g = tid>>5 -> rows g*8..g*8+7; 32 rows/block
__global__ void gemm_h_w2(const float* __restrict__ agg, const float* __restrict__ b1,
                          const float* __restrict__ W2, float* __restrict__ h2, int N) {
    __shared__ float xs[32][HID_DIM];   // 16 KB
    const int row0 = blockIdx.x * 32;
    const int tid  = threadIdx.x;
    {
        const int base = tid * 32;
        if (row0 + 32 <= N) {
            const float* s = agg + (long long)row0 * HID_DIM;
            #pragma unroll
            for (int i = 0; i < 8; ++i) {
                int idx = base + i * 4, col = idx & 127;
                float4 v = *(const float4*)(s + idx);
                const float4 b = *(const float4*)(b1 + col);
                v.x = fmaxf(v.x + b.x, 0.f); v.y = fmaxf(v.y + b.y, 0.f);
                v.z = fmaxf(v.z + b.z, 0.f); v.w = fmaxf(v.w + b.w, 0.f);
                *(float4*)(&xs[0][0] + idx) = v;
            }
        } else {
            #pragma unroll
            for (int i = 0; i < 32; ++i) {
                int idx = base + i, r = idx >> 7, col = idx & 127;
                float v = 0.f;
                if (row0 + r < N)
                    v = fmaxf(agg[(long long)(row0 + r) * HID_DIM + col] + b1[col], 0.f);
                (&xs[0][0])[idx] = v;
            }
        }
    }
    __syncthreads();
    const int c = tid & 31;
    const int g = tid >> 5;
    float acc0[8] = {0,0,0,0,0,0,0,0};
    float acc1[8] = {0,0,0,0,0,0,0,0};
    const float* Wc = W2 + c;
    for (int k = 0; k < HID_DIM; k += 4) {
        const float wa0 = Wc[(k+0)*OUT_DIM],      wa1 = Wc[(k+1)*OUT_DIM];
        const float wa2 = Wc[(k+2)*OUT_DIM],      wa3 = Wc[(k+3)*OUT_DIM];
        const float wb0 = Wc[(k+0)*OUT_DIM + 32], wb1 = Wc[(k+1)*OUT_DIM + 32];
        const float wb2 = Wc[(k+2)*OUT_DIM + 32], wb3 = Wc[(k+3)*OUT_DIM + 32];
        #pragma unroll
        for (int r = 0; r < 8; ++r) {
            const float4 xv = *(const float4*)(&xs[g * 8 + r][k]);
            acc0[r] += xv.x * wa0 + xv.y * wa1 + xv.z * wa2 + xv.w * wa3;
            acc1[r] += xv.x * wb0 + xv.y * wb1 + xv.z * wb2 + xv.w * wb3;
        }
    }
    #pragma unroll
    for (int r = 0; r < 8; ++r) {
        int row = row0 + g * 8 + r;
        if (row < N) {
            h2[(long long)row * OUT_DIM + c]      = acc0[r];
            h2[(long long)row * OUT_DIM + c + 32] = acc1[r];
        }
    }
}

// ---------------- gather aggregation (no atomics), branch-free unroll-8 ----------------
template<int D, int NPB>
__global__ void gather_nodes(const float* __restrict__ h, const int* __restrict__ srcSorted,
                             const int* __restrict__ row_start, const int* __restrict__ cnt,
                             const float* __restrict__ dinv, const float* __restrict__ bias,
                             int N, float* __restrict__ out) {
    const int TPN = D / 4;
    const int t = threadIdx.x;
    const int node = blockIdx.x * NPB + t / TPN;
    if (node >= N) return;
    const int f = (t & (TPN - 1)) * 4;
    const float dd = dinv[node];

    const float4 self = *(const float4*)(h + (long long)node * D + f);
    const float sn = dd * dd;
    float4 acc;
    acc.x = self.x * sn; acc.y = self.y * sn; acc.z = self.z * sn; acc.w = self.w * sn;
    if (bias) {
        const float4 b = *(const float4*)(bias + f);
        acc.x += b.x; acc.y += b.y; acc.z += b.z; acc.w += b.w;
    }

    const int start = row_start[node];
    const int end   = start + cnt[node];
    for (int e = start; e < end; e += 8) {
        #pragma unroll
        for (int i = 0; i < 8; ++i) {
            const bool ok = (e + i < end);
            const int idx = ok ? (e + i) : start;     // safe, cached address
            const int s = srcSorted[idx];
            const float n = ok ? dinv[s] * dd : 0.0f;
            const float4 v = *(const float4*)(h + (long long)s * D + f);
            acc.x += v.x * n; acc.y += v.y * n; acc.z += v.z * n; acc.w += v.w * n;
        }
    }
    *(float4*)(out + (long long)node * D + f) = acc;
}

extern "C" void kernel_launch(void* const* d_in, const int* in_sizes, int n_in,
                              void* d_out, int out_size, void* d_ws, size_t ws_size,
                              hipStream_t stream) {
    const float* x   = (const float*)d_in[0];
    const int*   ei  = (const int*)  d_in[1];
    const float* W1  = (const float*)d_in[2];
    const float* b1  = (const float*)d_in[3];
    const float* W2  = (const float*)d_in[4];
    const float* b2  = (const float*)d_in[5];
    float* out = (float*)d_out;

    const int N = in_sizes[0] / IN_DIM;     // 100000
    const int E = in_sizes[1] / 2;          // 1600000
    const int* src = ei;                    // edge_index[0]
    const int* dst = ei + E;                // edge_index[1]

    // workspace layout:
    // dinv[N] f32 | cnt[N] i32 | row_start[N] i32 | bsum[1024] i32 | srcSorted[E] i32
    // | bufA[N*128] f32 | bufB[N*128] f32     (rank aliases bufB's first E ints)
    float* dinv      = (float*)d_ws;
    int*   cnt       = (int*)(dinv + N);
    int*   row_start = cnt + N;
    int*   bsum      = row_start + N;
    int*   srcSorted = bsum + 1024;
    float* bufA      = (float*)(srcSorted + E);
    float* bufB      = bufA + (long long)N * HID_DIM;
    int*   rank      = (int*)bufB;          // alive only until fill_csr
    float* h1   = bufA;
    float* agg1 = bufB;                     // overwrites rank (after fill_csr)
    float* h2   = bufA;                     // overwrites h1 (after gather1)

    const int B = 256;
    const int S = (N + 2047) / 2048;        // scan blocks

    // 1) CSR build + dinv
    hipMemsetAsync(cnt, 0, (size_t)N * sizeof(int), stream);
    count_rank<<<(E + B - 1) / B, B, 0, stream>>>(dst, E, cnt, rank);
    make_dinv<<<(N + B - 1) / B, B, 0, stream>>>(cnt, dinv, N);
    scan_partial<<<S, 256, 0, stream>>>(cnt, bsum, N);
    scan_partials<<<1, 64, 0, stream>>>(bsum, S);
    scan_write<<<S, 256, 0, stream>>>(cnt, bsum, row_start, N);
    fill_csr<<<(E + B - 1) / B, B, 0, stream>>>(src, dst, rank, row_start, E, srcSorted);

    // 2) h1 = x @ W1
    gemm_x_w1<<<(N + 15) / 16, 128, 0, stream>>>(x, W1, h1, N);

    // 3) agg1 = gather(h1)
    gather_nodes<HID_DIM, 8><<<(N + 7) / 8, 256, 0, stream>>>(
        h1, srcSorted, row_start, cnt, dinv, nullptr, N, agg1);

    // 4) h2 = relu(agg1 + b1) @ W2
    gemm_h_w2<<<(N + 31) / 32, 128, 0, stream>>>(agg1, b1, W2, h2, N);

    // 5) out = b2 + gather(h2)
    gather_nodes<OUT_DIM, 16><<<(N + 15) / 16, 256, 0, stream>>>(
        h2, srcSorted, row_start, cnt, dinv, b2, N, out);
}

// Round 4
// 478.227 us; speedup vs baseline: 9.4698x; 1.1967x over previous
//
#include <hip/hip_runtime.h>
#include <hip/hip_bf16.h>

#define IN_DIM  128
#define HID_DIM 128
#define OUT_DIM 64

typedef unsigned short ushort_t;
struct ushort4_t { ushort_t x, y, z, w; };

__device__ __forceinline__ float bf2f(ushort_t u) {
    return __uint_as_float(((unsigned int)u) << 16);
}

// ---------------- degree count + per-edge rank ----------------
__global__ void count_rank(const int* __restrict__ dst, int E,
                           int* __restrict__ cnt, int* __restrict__ rank) {
    int e = blockIdx.x * blockDim.x + threadIdx.x;
    if (e < E) rank[e] = atomicAdd(&cnt[dst[e]], 1);
}

__global__ void make_dinv(const int* __restrict__ cnt, float* __restrict__ dinv, int N) {
    int i = blockIdx.x * blockDim.x + threadIdx.x;
    if (i < N) dinv[i] = rsqrtf((float)(cnt[i] + 1));  // +1 self loop
}

// ---------------- 3-kernel scan over cnt[N] (chunk = 2048/block) ----------------
__global__ void scan_partial(const int* __restrict__ cnt, int* __restrict__ bsum, int N) {
    __shared__ int wsum[4];
    const int t = threadIdx.x;
    const int base = blockIdx.x * 2048 + t * 8;
    int s = 0;
    #pragma unroll
    for (int i = 0; i < 8; ++i) s += (base + i < N) ? cnt[base + i] : 0;
    #pragma unroll
    for (int off = 32; off > 0; off >>= 1) s += __shfl_down(s, off);
    const int lane = t & 63, w = t >> 6;
    if (lane == 0) wsum[w] = s;
    __syncthreads();
    if (t == 0) bsum[blockIdx.x] = wsum[0] + wsum[1] + wsum[2] + wsum[3];
}

__global__ void scan_partials(int* __restrict__ bsum, int S) {
    const int t = threadIdx.x;  // 64 threads, single wave
    int running = 0;
    for (int base = 0; base < S; base += 64) {
        int i = base + t;
        int v = (i < S) ? bsum[i] : 0;
        int incl = v;
        #pragma unroll
        for (int off = 1; off < 64; off <<= 1) {
            int u = __shfl_up(incl, off);
            if (t >= off) incl += u;
        }
        if (i < S) bsum[i] = running + incl - v;   // exclusive
        running += __shfl(incl, 63);
    }
}

__global__ void scan_write(const int* __restrict__ cnt, const int* __restrict__ bsum,
                           int* __restrict__ row_start, int N) {
    __shared__ int wsum[4];
    const int t = threadIdx.x;
    const int base = blockIdx.x * 2048 + t * 8;
    int v[8];
    #pragma unroll
    for (int i = 0; i < 8; ++i) v[i] = (base + i < N) ? cnt[base + i] : 0;
    int s = v[0] + v[1] + v[2] + v[3] + v[4] + v[5] + v[6] + v[7];
    const int lane = t & 63, w = t >> 6;
    int incl = s;
    #pragma unroll
    for (int off = 1; off < 64; off <<= 1) {
        int u = __shfl_up(incl, off);
        if (lane >= off) incl += u;
    }
    if (lane == 63) wsum[w] = incl;
    __syncthreads();
    int woff = 0;
    for (int i = 0; i < w; ++i) woff += wsum[i];
    int run = bsum[blockIdx.x] + woff + (incl - s);
    #pragma unroll
    for (int i = 0; i < 8; ++i) {
        if (base + i < N) row_start[base + i] = run;
        run += v[i];
    }
}

// ---------------- fill packed CSR records {src, norm} (no atomics) ----------------
__global__ void fill_pack(const int* __restrict__ src, const int* __restrict__ dst,
                          const int* __restrict__ rank, const int* __restrict__ row_start,
                          const float* __restrict__ dinv, int E, int2* __restrict__ pack) {
    int e = blockIdx.x * blockDim.x + threadIdx.x;
    if (e < E) {
        int s = src[e], d = dst[e];
        int2 p;
        p.x = s;
        p.y = __float_as_int(dinv[s] * dinv[d]);
        pack[row_start[d] + rank[e]] = p;
    }
}

// ---------------- GEMM1: h1[N,128](bf16) = x[N,128] @ W1[128,128] ----------------
// block 128: c = tid&63 -> cols {c, c+64}; g = tid>>6 -> rows g*8..g*8+7; 16 rows/block
__global__ void gemm_x_w1(const float* __restrict__ x, const float* __restrict__ W,
                          __hip_bfloat16* __restrict__ h, int N) {
    __shared__ float xs[16][IN_DIM];
    const int row0 = blockIdx.x * 16;
    const int tid  = threadIdx.x;
    {
        const int base = tid * 16;
        if (row0 + 16 <= N) {
            const float* s = x + (long long)row0 * IN_DIM;
            #pragma unroll
            for (int i = 0; i < 4; ++i)
                *(float4*)(&xs[0][0] + base + i * 4) = *(const float4*)(s + base + i * 4);
        } else {
            #pragma unroll
            for (int i = 0; i < 16; ++i) {
                int idx = base + i, r = idx >> 7, col = idx & 127;
                (&xs[0][0])[idx] = (row0 + r < N)
                    ? x[(long long)(row0 + r) * IN_DIM + col] : 0.0f;
            }
        }
    }
    __syncthreads();
    const int c = tid & 63;
    const int g = tid >> 6;
    float acc0[8] = {0,0,0,0,0,0,0,0};
    float acc1[8] = {0,0,0,0,0,0,0,0};
    const float* Wc = W + c;
    for (int k = 0; k < IN_DIM; k += 4) {
        const float wa0 = Wc[(k+0)*HID_DIM],      wa1 = Wc[(k+1)*HID_DIM];
        const float wa2 = Wc[(k+2)*HID_DIM],      wa3 = Wc[(k+3)*HID_DIM];
        const float wb0 = Wc[(k+0)*HID_DIM + 64], wb1 = Wc[(k+1)*HID_DIM + 64];
        const float wb2 = Wc[(k+2)*HID_DIM + 64], wb3 = Wc[(k+3)*HID_DIM + 64];
        #pragma unroll
        for (int r = 0; r < 8; ++r) {
            const float4 xv = *(const float4*)(&xs[g * 8 + r][k]);
            acc0[r] += xv.x * wa0 + xv.y * wa1 + xv.z * wa2 + xv.w * wa3;
            acc1[r] += xv.x * wb0 + xv.y * wb1 + xv.z * wb2 + xv.w * wb3;
        }
    }
    #pragma unroll
    for (int r = 0; r < 8; ++r) {
        int row = row0 + g * 8 + r;
        if (row < N) {
            h[(long long)row * HID_DIM + c]      = __float2bfloat16(acc0[r]);
            h[(long long)row * HID_DIM + c + 64] = __float2bfloat16(acc1[r]);
        }
    }
}

// ---------------- GEMM2: h2[N,64](bf16) = relu(agg + b1) @ W2[128,64] ----------------
// block 128: c = tid&31 -> cols {c, c+32}; g = tid>>5 -> rows g*8..g*8+7; 32 rows/block
__global__ void gemm_h_w2(const float* __restrict__ agg, const float* __restrict__ b1,
                          const float* __restrict__ W2, __hip_bfloat16* __restrict__ h2, int N) {
    __shared__ float xs[32][HID_DIM];   // 16 KB
    const int row0 = blockIdx.x * 32;
    const int tid  = threadIdx.x;
    {
        const int base = tid * 32;
        if (row0 + 32 <= N) {
            const float* s = agg + (long long)row0 * HID_DIM;
            #pragma unroll
            for (int i = 0; i < 8; ++i) {
                int idx = base + i * 4, col = idx & 127;
                float4 v = *(const float4*)(s + idx);
                const float4 b = *(const float4*)(b1 + col);
                v.x = fmaxf(v.x + b.x, 0.f); v.y = fmaxf(v.y + b.y, 0.f);
                v.z = fmaxf(v.z + b.z, 0.f); v.w = fmaxf(v.w + b.w, 0.f);
                *(float4*)(&xs[0][0] + idx) = v;
            }
        } else {
            #pragma unroll
            for (int i = 0; i < 32; ++i) {
                int idx = base + i, r = idx >> 7, col = idx & 127;
                float v = 0.f;
                if (row0 + r < N)
                    v = fmaxf(agg[(long long)(row0 + r) * HID_DIM + col] + b1[col], 0.f);
                (&xs[0][0])[idx] = v;
            }
        }
    }
    __syncthreads();
    const int c = tid & 31;
    const int g = tid >> 5;
    float acc0[8] = {0,0,0,0,0,0,0,0};
    float acc1[8] = {0,0,0,0,0,0,0,0};
    const float* Wc = W2 + c;
    for (int k = 0; k < HID_DIM; k += 4) {
        const float wa0 = Wc[(k+0)*OUT_DIM],      wa1 = Wc[(k+1)*OUT_DIM];
        const float wa2 = Wc[(k+2)*OUT_DIM],      wa3 = Wc[(k+3)*OUT_DIM];
        const float wb0 = Wc[(k+0)*OUT_DIM + 32], wb1 = Wc[(k+1)*OUT_DIM + 32];
        const float wb2 = Wc[(k+2)*OUT_DIM + 32], wb3 = Wc[(k+3)*OUT_DIM + 32];
        #pragma unroll
        for (int r = 0; r < 8; ++r) {
            const float4 xv = *(const float4*)(&xs[g * 8 + r][k]);
            acc0[r] += xv.x * wa0 + xv.y * wa1 + xv.z * wa2 + xv.w * wa3;
            acc1[r] += xv.x * wb0 + xv.y * wb1 + xv.z * wb2 + xv.w * wb3;
        }
    }
    #pragma unroll
    for (int r = 0; r < 8; ++r) {
        int row = row0 + g * 8 + r;
        if (row < N) {
            h2[(long long)row * OUT_DIM + c]      = __float2bfloat16(acc0[r]);
            h2[(long long)row * OUT_DIM + c + 32] = __float2bfloat16(acc1[r]);
        }
    }
}

// ---------------- gather aggregation, bf16 messages, packed records ----------------
// out[i] = (bias) + dinv[i]^2 * h[i] + sum_{e in CSR[i]} norm[e] * h[src[e]]
// TPN = D/4 threads per node; ushort4 (4 bf16) per thread; f32 accumulate.
template<int D>
__global__ void gather_bf16(const ushort_t* __restrict__ h, const int2* __restrict__ pack,
                            const int* __restrict__ row_start, const int* __restrict__ cnt,
                            const float* __restrict__ dinv, const float* __restrict__ bias,
                            int N, float* __restrict__ out) {
    const int TPN = D / 4;
    const int NPB = 256 / TPN;
    const int t = threadIdx.x;
    const int node = blockIdx.x * NPB + t / TPN;
    if (node >= N) return;
    const int f = (t & (TPN - 1)) * 4;
    const float dd = dinv[node];

    const ushort4_t self = *(const ushort4_t*)(h + (long long)node * D + f);
    const float sn = dd * dd;
    float4 acc;
    acc.x = bf2f(self.x) * sn; acc.y = bf2f(self.y) * sn;
    acc.z = bf2f(self.z) * sn; acc.w = bf2f(self.w) * sn;
    if (bias) {
        const float4 b = *(const float4*)(bias + f);
        acc.x += b.x; acc.y += b.y; acc.z += b.z; acc.w += b.w;
    }

    const int start = row_start[node];
    const int end   = start + cnt[node];
    for (int e = start; e < end; e += 4) {
        #pragma unroll
        for (int i = 0; i < 4; ++i) {
            const bool ok = (e + i < end);
            const int2 p = pack[ok ? (e + i) : start];
            const int   s = ok ? p.x : node;                 // dead lanes hit own (L1-hot) row
            const float n = ok ? __int_as_float(p.y) : 0.0f;
            const ushort4_t v = *(const ushort4_t*)(h + (long long)s * D + f);
            acc.x += bf2f(v.x) * n; acc.y += bf2f(v.y) * n;
            acc.z += bf2f(v.z) * n; acc.w += bf2f(v.w) * n;
        }
    }
    *(float4*)(out + (long long)node * D + f) = acc;
}

extern "C" void kernel_launch(void* const* d_in, const int* in_sizes, int n_in,
                              void* d_out, int out_size, void* d_ws, size_t ws_size,
                              hipStream_t stream) {
    const float* x   = (const float*)d_in[0];
    const int*   ei  = (const int*)  d_in[1];
    const float* W1  = (const float*)d_in[2];
    const float* b1  = (const float*)d_in[3];
    const float* W2  = (const float*)d_in[4];
    const float* b2  = (const float*)d_in[5];
    float* out = (float*)d_out;

    const int N = in_sizes[0] / IN_DIM;     // 100000
    const int E = in_sizes[1] / 2;          // 1600000
    const int* src = ei;                    // edge_index[0]
    const int* dst = ei + E;                // edge_index[1]

    // workspace layout (4B units):
    // dinv[N] f32 | cnt[N] i32 | row_start[N] i32 | bsum[1024] i32 | pack[E] int2 (2E)
    // | h1[N*128] bf16 (= N*64 u32, reused as h2) | agg1[N*128] f32 (rank aliases it)
    float* dinv      = (float*)d_ws;
    int*   cnt       = (int*)(dinv + N);
    int*   row_start = cnt + N;
    int*   bsum      = row_start + N;
    int2*  pack      = (int2*)(bsum + 1024);
    __hip_bfloat16* h1 = (__hip_bfloat16*)(pack + E);
    float* agg1      = (float*)((int*)h1 + (long long)N * HID_DIM / 2);
    int*   rank      = (int*)agg1;          // alive only until fill_pack
    __hip_bfloat16* h2 = h1;                // reuse after gather128

    const int B = 256;
    const int S = (N + 2047) / 2048;        // scan blocks

    // 1) CSR build + dinv
    hipMemsetAsync(cnt, 0, (size_t)N * sizeof(int), stream);
    count_rank<<<(E + B - 1) / B, B, 0, stream>>>(dst, E, cnt, rank);
    make_dinv<<<(N + B - 1) / B, B, 0, stream>>>(cnt, dinv, N);
    scan_partial<<<S, 256, 0, stream>>>(cnt, bsum, N);
    scan_partials<<<1, 64, 0, stream>>>(bsum, S);
    scan_write<<<S, 256, 0, stream>>>(cnt, bsum, row_start, N);
    fill_pack<<<(E + B - 1) / B, B, 0, stream>>>(src, dst, rank, row_start, dinv, E, pack);

    // 2) h1 = x @ W1  (bf16 out)
    gemm_x_w1<<<(N + 15) / 16, 128, 0, stream>>>(x, W1, h1, N);

    // 3) agg1 = gather(h1)  (f32 accum/out; overwrites rank)
    gather_bf16<HID_DIM><<<(N + 7) / 8, 256, 0, stream>>>(
        (const ushort_t*)h1, pack, row_start, cnt, dinv, nullptr, N, agg1);

    // 4) h2 = relu(agg1 + b1) @ W2  (bf16 out)
    gemm_h_w2<<<(N + 31) / 32, 128, 0, stream>>>(agg1, b1, W2, h2, N);

    // 5) out = b2 + gather(h2)  (f32 out)
    gather_bf16<OUT_DIM><<<(N + 15) / 16, 256, 0, stream>>>(
        (const ushort_t*)h2, pack, row_start, cnt, dinv, b2, N, out);
}

// Round 5
// 437.552 us; speedup vs baseline: 10.3501x; 1.0930x over previous
//
#include <hip/hip_runtime.h>
#include <hip/hip_bf16.h>

#define IN_DIM  128
#define HID_DIM 128
#define OUT_DIM 64

typedef unsigned short ushort_t;
struct ushort4_t { ushort_t x, y, z, w; };

__device__ __forceinline__ float bf2f(ushort_t u) {
    return __uint_as_float(((unsigned int)u) << 16);
}
__device__ __forceinline__ ushort_t f2bf_bits(float v) {
    __hip_bfloat16 t = __float2bfloat16(v);
    return *(ushort_t*)&t;
}

// ---------------- degree count + per-edge rank ----------------
__global__ void count_rank(const int* __restrict__ dst, int E,
                           int* __restrict__ cnt, int* __restrict__ rank) {
    int e = blockIdx.x * blockDim.x + threadIdx.x;
    if (e < E) rank[e] = atomicAdd(&cnt[dst[e]], 1);
}

__global__ void make_dinv(const int* __restrict__ cnt, float* __restrict__ dinv, int N) {
    int i = blockIdx.x * blockDim.x + threadIdx.x;
    if (i < N) dinv[i] = rsqrtf((float)(cnt[i] + 1));  // +1 self loop
}

// ---------------- 3-kernel scan over PADDED counts ((cnt+3)&~3) ----------------
__global__ void scan_partial(const int* __restrict__ cnt, int* __restrict__ bsum, int N) {
    __shared__ int wsum[4];
    const int t = threadIdx.x;
    const int base = blockIdx.x * 2048 + t * 8;
    int s = 0;
    #pragma unroll
    for (int i = 0; i < 8; ++i) s += (base + i < N) ? ((cnt[base + i] + 3) & ~3) : 0;
    #pragma unroll
    for (int off = 32; off > 0; off >>= 1) s += __shfl_down(s, off);
    const int lane = t & 63, w = t >> 6;
    if (lane == 0) wsum[w] = s;
    __syncthreads();
    if (t == 0) bsum[blockIdx.x] = wsum[0] + wsum[1] + wsum[2] + wsum[3];
}

__global__ void scan_partials(int* __restrict__ bsum, int S) {
    const int t = threadIdx.x;  // 64 threads, single wave
    int running = 0;
    for (int base = 0; base < S; base += 64) {
        int i = base + t;
        int v = (i < S) ? bsum[i] : 0;
        int incl = v;
        #pragma unroll
        for (int off = 1; off < 64; off <<= 1) {
            int u = __shfl_up(incl, off);
            if (t >= off) incl += u;
        }
        if (i < S) bsum[i] = running + incl - v;   // exclusive
        running += __shfl(incl, 63);
    }
}

__global__ void scan_write(const int* __restrict__ cnt, const int* __restrict__ bsum,
                           int* __restrict__ row_start, int N) {
    __shared__ int wsum[4];
    const int t = threadIdx.x;
    const int base = blockIdx.x * 2048 + t * 8;
    int v[8];
    #pragma unroll
    for (int i = 0; i < 8; ++i) v[i] = (base + i < N) ? ((cnt[base + i] + 3) & ~3) : 0;
    int s = v[0] + v[1] + v[2] + v[3] + v[4] + v[5] + v[6] + v[7];
    const int lane = t & 63, w = t >> 6;
    int incl = s;
    #pragma unroll
    for (int off = 1; off < 64; off <<= 1) {
        int u = __shfl_up(incl, off);
        if (lane >= off) incl += u;
    }
    if (lane == 63) wsum[w] = incl;
    __syncthreads();
    int woff = 0;
    for (int i = 0; i < w; ++i) woff += wsum[i];
    int run = bsum[blockIdx.x] + woff + (incl - s);
    #pragma unroll
    for (int i = 0; i < 8; ++i) {
        if (base + i < N) row_start[base + i] = run;
        run += v[i];
    }
}

// ---------------- fill packed CSR records {src, norm} (no atomics) ----------------
// pack[] pre-zeroed; padded slots stay {0, 0.0f} -> contribute nothing.
__global__ void fill_pack(const int* __restrict__ src, const int* __restrict__ dst,
                          const int* __restrict__ rank, const int* __restrict__ row_start,
                          const float* __restrict__ dinv, int E, int2* __restrict__ pack) {
    int e = blockIdx.x * blockDim.x + threadIdx.x;
    if (e < E) {
        int s = src[e], d = dst[e];
        int2 p;
        p.x = s;
        p.y = __float_as_int(dinv[s] * dinv[d]);
        pack[row_start[d] + rank[e]] = p;
    }
}

// ---------------- GEMM1: h1[N,128](bf16) = x[N,128] @ W1[128,128] ----------------
// block 256 = 4 waves; lane owns one of 64 rows, wave owns a 32-col slab.
// W loads are wave-uniform -> scalar path; LDS traffic: 32 ds_read_b128/lane total.
#define XSS 132   // padded row stride (floats): conflict-free lane-strided b128 reads
__global__ __launch_bounds__(256) void gemm_x_w1(const float* __restrict__ x,
                                                 const float* __restrict__ W,
                                                 unsigned int* __restrict__ h, int N) {
    __shared__ float xs[64 * XSS];  // 33.8 KB
    const int row0 = blockIdx.x * 64;
    const int tid  = threadIdx.x;
    if (row0 + 64 <= N) {
        const float* s = x + (size_t)row0 * IN_DIM;
        #pragma unroll
        for (int j = 0; j < 8; ++j) {
            int fidx = j * 1024 + tid * 4;
            int r = fidx >> 7, c = fidx & 127;
            *(float4*)&xs[r * XSS + c] = *(const float4*)(s + fidx);
        }
    } else {
        #pragma unroll
        for (int j = 0; j < 8; ++j) {
            int fidx = j * 1024 + tid * 4;
            int r = fidx >> 7, c = fidx & 127;
            float4 v = {0.f, 0.f, 0.f, 0.f};
            if (row0 + r < N) v = *(const float4*)(x + (size_t)(row0 + r) * IN_DIM + c);
            *(float4*)&xs[r * XSS + c] = v;
        }
    }
    __syncthreads();

    const int lane  = tid & 63;
    const int wbase = __builtin_amdgcn_readfirstlane(tid >> 6) * 32;  // uniform col base
    float acc[32];
    #pragma unroll
    for (int j = 0; j < 32; ++j) acc[j] = 0.f;
    const float* xrow = &xs[lane * XSS];

    for (int k4 = 0; k4 < IN_DIM; k4 += 4) {
        const float4 xv = *(const float4*)(xrow + k4);
        #pragma unroll
        for (int i = 0; i < 4; ++i) {
            const float xk = (i == 0) ? xv.x : (i == 1) ? xv.y : (i == 2) ? xv.z : xv.w;
            const float4* wr = (const float4*)(W + (size_t)(k4 + i) * HID_DIM + wbase);
            #pragma unroll
            for (int j = 0; j < 8; ++j) {
                const float4 wv = wr[j];    // wave-uniform -> s_load
                acc[j*4+0] += xk * wv.x; acc[j*4+1] += xk * wv.y;
                acc[j*4+2] += xk * wv.z; acc[j*4+3] += xk * wv.w;
            }
        }
    }
    const int row = row0 + lane;
    if (row < N) {
        unsigned int* o = h + (size_t)row * (HID_DIM / 2) + wbase / 2;
        #pragma unroll
        for (int j = 0; j < 16; ++j)
            o[j] = ((unsigned int)f2bf_bits(acc[2*j+1]) << 16) | f2bf_bits(acc[2*j]);
    }
}

// ---------------- GEMM2: h2[N,64](bf16) = relu(agg + b1) @ W2[128,64] ----------------
// block 256 = 4 waves; lane owns one of 64 rows, wave owns a 16-col slab.
__global__ __launch_bounds__(256) void gemm_h_w2(const float* __restrict__ agg,
                                                 const float* __restrict__ b1,
                                                 const float* __restrict__ W2,
                                                 unsigned int* __restrict__ h2, int N) {
    __shared__ float xs[64 * XSS];  // 33.8 KB
    const int row0 = blockIdx.x * 64;
    const int tid  = threadIdx.x;
    {
        #pragma unroll
        for (int j = 0; j < 8; ++j) {
            int fidx = j * 1024 + tid * 4;
            int r = fidx >> 7, c = fidx & 127;
            float4 v = {0.f, 0.f, 0.f, 0.f};
            if (row0 + r < N) {
                v = *(const float4*)(agg + (size_t)(row0 + r) * HID_DIM + c);
                const float4 b = *(const float4*)(b1 + c);
                v.x = fmaxf(v.x + b.x, 0.f); v.y = fmaxf(v.y + b.y, 0.f);
                v.z = fmaxf(v.z + b.z, 0.f); v.w = fmaxf(v.w + b.w, 0.f);
            }
            *(float4*)&xs[r * XSS + c] = v;
        }
    }
    __syncthreads();

    const int lane  = tid & 63;
    const int wbase = __builtin_amdgcn_readfirstlane(tid >> 6) * 16;  // uniform col base
    float acc[16];
    #pragma unroll
    for (int j = 0; j < 16; ++j) acc[j] = 0.f;
    const float* xrow = &xs[lane * XSS];

    for (int k4 = 0; k4 < HID_DIM; k4 += 4) {
        const float4 xv = *(const float4*)(xrow + k4);
        #pragma unroll
        for (int i = 0; i < 4; ++i) {
            const float xk = (i == 0) ? xv.x : (i == 1) ? xv.y : (i == 2) ? xv.z : xv.w;
            const float4* wr = (const float4*)(W2 + (size_t)(k4 + i) * OUT_DIM + wbase);
            #pragma unroll
            for (int j = 0; j < 4; ++j) {
                const float4 wv = wr[j];    // wave-uniform -> s_load
                acc[j*4+0] += xk * wv.x; acc[j*4+1] += xk * wv.y;
                acc[j*4+2] += xk * wv.z; acc[j*4+3] += xk * wv.w;
            }
        }
    }
    const int row = row0 + lane;
    if (row < N) {
        unsigned int* o = h2 + (size_t)row * (OUT_DIM / 2) + wbase / 2;
        #pragma unroll
        for (int j = 0; j < 8; ++j)
            o[j] = ((unsigned int)f2bf_bits(acc[2*j+1]) << 16) | f2bf_bits(acc[2*j]);
    }
}

// ---------------- gather aggregation, bf16 messages, padded packed records ----------------
// Rows padded to multiples of 4 records; pad records are {0,0.0f} -> no-op.
template<int D>
__global__ void gather_bf16(const ushort_t* __restrict__ h, const int2* __restrict__ pack,
                            const int* __restrict__ row_start, const int* __restrict__ cnt,
                            const float* __restrict__ dinv, const float* __restrict__ bias,
                            int N, float* __restrict__ out) {
    const int TPN = D / 4;
    const int NPB = 256 / TPN;
    const int t = threadIdx.x;
    const int node = blockIdx.x * NPB + t / TPN;
    if (node >= N) return;
    const int f = (t & (TPN - 1)) * 4;
    const float dd = dinv[node];

    const ushort4_t self = *(const ushort4_t*)(h + (size_t)node * D + f);
    const float sn = dd * dd;
    float4 acc;
    acc.x = bf2f(self.x) * sn; acc.y = bf2f(self.y) * sn;
    acc.z = bf2f(self.z) * sn; acc.w = bf2f(self.w) * sn;
    if (bias) {
        const float4 b = *(const float4*)(bias + f);
        acc.x += b.x; acc.y += b.y; acc.z += b.z; acc.w += b.w;
    }

    const int2* pk = pack + row_start[node];       // 16B-aligned (start % 4 == 0)
    const int cpad = (cnt[node] + 3) & ~3;
    for (int e = 0; e < cpad; e += 4) {
        const int4 a = *(const int4*)(pk + e);
        const int4 b = *(const int4*)(pk + e + 2);
        {
            const ushort4_t v = *(const ushort4_t*)(h + (size_t)a.x * D + f);
            const float n = __int_as_float(a.y);
            acc.x += bf2f(v.x) * n; acc.y += bf2f(v.y) * n;
            acc.z += bf2f(v.z) * n; acc.w += bf2f(v.w) * n;
        }
        {
            const ushort4_t v = *(const ushort4_t*)(h + (size_t)a.z * D + f);
            const float n = __int_as_float(a.w);
            acc.x += bf2f(v.x) * n; acc.y += bf2f(v.y) * n;
            acc.z += bf2f(v.z) * n; acc.w += bf2f(v.w) * n;
        }
        {
            const ushort4_t v = *(const ushort4_t*)(h + (size_t)b.x * D + f);
            const float n = __int_as_float(b.y);
            acc.x += bf2f(v.x) * n; acc.y += bf2f(v.y) * n;
            acc.z += bf2f(v.z) * n; acc.w += bf2f(v.w) * n;
        }
        {
            const ushort4_t v = *(const ushort4_t*)(h + (size_t)b.z * D + f);
            const float n = __int_as_float(b.w);
            acc.x += bf2f(v.x) * n; acc.y += bf2f(v.y) * n;
            acc.z += bf2f(v.z) * n; acc.w += bf2f(v.w) * n;
        }
    }
    *(float4*)(out + (size_t)node * D + f) = acc;
}

extern "C" void kernel_launch(void* const* d_in, const int* in_sizes, int n_in,
                              void* d_out, int out_size, void* d_ws, size_t ws_size,
                              hipStream_t stream) {
    const float* x   = (const float*)d_in[0];
    const int*   ei  = (const int*)  d_in[1];
    const float* W1  = (const float*)d_in[2];
    const float* b1  = (const float*)d_in[3];
    const float* W2  = (const float*)d_in[4];
    const float* b2  = (const float*)d_in[5];
    float* out = (float*)d_out;

    const int N = in_sizes[0] / IN_DIM;     // 100000
    const int E = in_sizes[1] / 2;          // 1600000
    const int* src = ei;                    // edge_index[0]
    const int* dst = ei + E;                // edge_index[1]

    // workspace layout (4B units):
    // dinv[N] | cnt[N] | row_start[N] | bsum[1024] | align pad | pack[(E+4N)] int2
    // | h1[N*64] u32 (bf16x2, reused as h2) | agg1[N*128] f32 (rank aliases it)
    const int PACK_CAP = E + 4 * N;         // >= sum of padded row lengths
    float* dinv      = (float*)d_ws;
    int*   cnt       = (int*)(dinv + N);
    int*   row_start = cnt + N;
    int*   bsum      = row_start + N;
    size_t off       = (size_t)(3 * N + 1024);
    off = (off + 3) & ~(size_t)3;           // 16B-align pack
    int2*  pack      = (int2*)((int*)d_ws + off);
    unsigned int* h1 = (unsigned int*)(pack + PACK_CAP);
    float* agg1      = (float*)(h1 + (size_t)N * (HID_DIM / 2));
    int*   rank      = (int*)agg1;          // alive only until fill_pack
    unsigned int* h2 = h1;                  // reuse after gather128

    const int B = 256;
    const int S = (N + 2047) / 2048;        // scan blocks

    // 1) CSR build + dinv
    hipMemsetAsync(cnt, 0, (size_t)N * sizeof(int), stream);
    hipMemsetAsync(pack, 0, (size_t)PACK_CAP * sizeof(int2), stream);
    count_rank<<<(E + B - 1) / B, B, 0, stream>>>(dst, E, cnt, rank);
    make_dinv<<<(N + B - 1) / B, B, 0, stream>>>(cnt, dinv, N);
    scan_partial<<<S, 256, 0, stream>>>(cnt, bsum, N);
    scan_partials<<<1, 64, 0, stream>>>(bsum, S);
    scan_write<<<S, 256, 0, stream>>>(cnt, bsum, row_start, N);
    fill_pack<<<(E + B - 1) / B, B, 0, stream>>>(src, dst, rank, row_start, dinv, E, pack);

    // 2) h1 = x @ W1  (bf16 out)
    gemm_x_w1<<<(N + 63) / 64, 256, 0, stream>>>(x, W1, h1, N);

    // 3) agg1 = gather(h1)  (f32 accum/out; overwrites rank)
    gather_bf16<HID_DIM><<<(N + 7) / 8, 256, 0, stream>>>(
        (const ushort_t*)h1, pack, row_start, cnt, dinv, nullptr, N, agg1);

    // 4) h2 = relu(agg1 + b1) @ W2  (bf16 out)
    gemm_h_w2<<<(N + 63) / 64, 256, 0, stream>>>(agg1, b1, W2, h2, N);

    // 5) out = b2 + gather(h2)  (f32 out)
    gather_bf16<OUT_DIM><<<(N + 15) / 16, 256, 0, stream>>>(
        (const ushort_t*)h2, pack, row_start, cnt, dinv, b2, N, out);
}

// Round 6
// 339.678 us; speedup vs baseline: 13.3324x; 1.2881x over previous
//
#include <hip/hip_runtime.h>
#include <hip/hip_bf16.h>

#define IN_DIM  128
#define HID_DIM 128
#define OUT_DIM 64

typedef unsigned short ushort_t;
struct ushort4_t { ushort_t x, y, z, w; };
typedef __attribute__((ext_vector_type(8))) short bf16x8;   // 8 bf16 (4 VGPRs)
typedef __attribute__((ext_vector_type(4))) float f32x4;    // MFMA acc

__device__ __forceinline__ float bf2f(ushort_t u) {
    return __uint_as_float(((unsigned int)u) << 16);
}
__device__ __forceinline__ short f2bf_s(float v) {
    __hip_bfloat16 t = __float2bfloat16(v);
    return *(short*)&t;
}
__device__ __forceinline__ unsigned int pack2(float a, float b) {
    return ((unsigned int)(ushort_t)f2bf_s(b) << 16) | (ushort_t)f2bf_s(a);
}

// ---------------- degree count + per-edge rank ----------------
__global__ void count_rank(const int* __restrict__ dst, int E,
                           int* __restrict__ cnt, int* __restrict__ rank) {
    int e = blockIdx.x * blockDim.x + threadIdx.x;
    if (e < E) rank[e] = atomicAdd(&cnt[dst[e]], 1);
}

__global__ void make_dinv(const int* __restrict__ cnt, float* __restrict__ dinv, int N) {
    int i = blockIdx.x * blockDim.x + threadIdx.x;
    if (i < N) dinv[i] = rsqrtf((float)(cnt[i] + 1));  // +1 self loop
}

// ---------------- 3-kernel scan over PADDED counts ((cnt+3)&~3) ----------------
__global__ void scan_partial(const int* __restrict__ cnt, int* __restrict__ bsum, int N) {
    __shared__ int wsum[4];
    const int t = threadIdx.x;
    const int base = blockIdx.x * 2048 + t * 8;
    int s = 0;
    #pragma unroll
    for (int i = 0; i < 8; ++i) s += (base + i < N) ? ((cnt[base + i] + 3) & ~3) : 0;
    #pragma unroll
    for (int off = 32; off > 0; off >>= 1) s += __shfl_down(s, off);
    const int lane = t & 63, w = t >> 6;
    if (lane == 0) wsum[w] = s;
    __syncthreads();
    if (t == 0) bsum[blockIdx.x] = wsum[0] + wsum[1] + wsum[2] + wsum[3];
}

__global__ void scan_partials(int* __restrict__ bsum, int S) {
    const int t = threadIdx.x;  // 64 threads, single wave
    int running = 0;
    for (int base = 0; base < S; base += 64) {
        int i = base + t;
        int v = (i < S) ? bsum[i] : 0;
        int incl = v;
        #pragma unroll
        for (int off = 1; off < 64; off <<= 1) {
            int u = __shfl_up(incl, off);
            if (t >= off) incl += u;
        }
        if (i < S) bsum[i] = running + incl - v;   // exclusive
        running += __shfl(incl, 63);
    }
}

__global__ void scan_write(const int* __restrict__ cnt, const int* __restrict__ bsum,
                           int* __restrict__ row_start, int N) {
    __shared__ int wsum[4];
    const int t = threadIdx.x;
    const int base = blockIdx.x * 2048 + t * 8;
    int v[8];
    #pragma unroll
    for (int i = 0; i < 8; ++i) v[i] = (base + i < N) ? ((cnt[base + i] + 3) & ~3) : 0;
    int s = v[0] + v[1] + v[2] + v[3] + v[4] + v[5] + v[6] + v[7];
    const int lane = t & 63, w = t >> 6;
    int incl = s;
    #pragma unroll
    for (int off = 1; off < 64; off <<= 1) {
        int u = __shfl_up(incl, off);
        if (lane >= off) incl += u;
    }
    if (lane == 63) wsum[w] = incl;
    __syncthreads();
    int woff = 0;
    for (int i = 0; i < w; ++i) woff += wsum[i];
    int run = bsum[blockIdx.x] + woff + (incl - s);
    #pragma unroll
    for (int i = 0; i < 8; ++i) {
        if (base + i < N) row_start[base + i] = run;
        run += v[i];
    }
}

// ---------------- fill packed CSR records {src, norm} (no atomics) ----------------
// pack[] pre-zeroed; padded slots stay {0, 0.0f} -> contribute nothing.
__global__ void fill_pack(const int* __restrict__ src, const int* __restrict__ dst,
                          const int* __restrict__ rank, const int* __restrict__ row_start,
                          const float* __restrict__ dinv, int E, int2* __restrict__ pack) {
    int e = blockIdx.x * blockDim.x + threadIdx.x;
    if (e < E) {
        int s = src[e], d = dst[e];
        int2 p;
        p.x = s;
        p.y = __float_as_int(dinv[s] * dinv[d]);
        pack[row_start[d] + rank[e]] = p;
    }
}

// ---------------- GEMM1 (MFMA): h1[N,128](bf16) = x[N,128] @ W1[128,128] ----------------
// Computes D = W1^T · x^T per 16-node tile. 4 waves/block, persistent grid-stride.
// A-frag (regs, loaded once): A[m=lane&15 -> hid][k=quad*8+j] = W1[k][hid].
// B-frag (per tile): B[k][n=lane&15 -> node] = x[node][k]  (2x float4 + cvt).
// D: col=lane&15 -> node, row=quad*4+reg -> 4 consecutive hid cols -> 8B store.
__global__ __launch_bounds__(256, 2) void gemm1_mfma(
        const float* __restrict__ x, const float* __restrict__ W,
        unsigned int* __restrict__ h, int N, int NT, int NW) {
    const int tid  = threadIdx.x;
    const int lane = tid & 63;
    const int m    = lane & 15;
    const int quad = lane >> 4;
    const int gw   = blockIdx.x * 4 + (tid >> 6);

    bf16x8 a[8][4];                         // 8 col-tiles x 4 k-chunks, 128 VGPRs
    #pragma unroll
    for (int ct = 0; ct < 8; ++ct)
        #pragma unroll
        for (int kc = 0; kc < 4; ++kc)
            #pragma unroll
            for (int j = 0; j < 8; ++j)
                a[ct][kc][j] = f2bf_s(W[(size_t)(kc * 32 + quad * 8 + j) * HID_DIM + ct * 16 + m]);

    for (int t = gw; t < NT; t += NW) {
        const int n0 = t * 16;
        int node = n0 + m; if (node >= N) node = N - 1;
        const float* xr = x + (size_t)node * IN_DIM + quad * 8;
        f32x4 acc[8];
        #pragma unroll
        for (int ct = 0; ct < 8; ++ct) acc[ct] = (f32x4){0.f, 0.f, 0.f, 0.f};
        #pragma unroll
        for (int kc = 0; kc < 4; ++kc) {
            const float4 v0 = *(const float4*)(xr + kc * 32);
            const float4 v1 = *(const float4*)(xr + kc * 32 + 4);
            bf16x8 b;
            b[0] = f2bf_s(v0.x); b[1] = f2bf_s(v0.y); b[2] = f2bf_s(v0.z); b[3] = f2bf_s(v0.w);
            b[4] = f2bf_s(v1.x); b[5] = f2bf_s(v1.y); b[6] = f2bf_s(v1.z); b[7] = f2bf_s(v1.w);
            #pragma unroll
            for (int ct = 0; ct < 8; ++ct)
                acc[ct] = __builtin_amdgcn_mfma_f32_16x16x32_bf16(a[ct][kc], b, acc[ct], 0, 0, 0);
        }
        if (n0 + m < N) {
            unsigned int* o = h + (size_t)(n0 + m) * (HID_DIM / 2) + quad * 2;
            #pragma unroll
            for (int ct = 0; ct < 8; ++ct) {
                uint2 pv;
                pv.x = pack2(acc[ct][0], acc[ct][1]);
                pv.y = pack2(acc[ct][2], acc[ct][3]);
                *(uint2*)(o + ct * 8) = pv;
            }
        }
    }
}

// ---------------- GEMM2 (MFMA): h2[N,64](bf16) = relu(agg(bf16) + b1) @ W2[128,64] ----------------
__global__ __launch_bounds__(256) void gemm2_mfma(
        const ushort_t* __restrict__ agg, const float* __restrict__ b1,
        const float* __restrict__ W2, unsigned int* __restrict__ h2,
        int N, int NT, int NW) {
    const int tid  = threadIdx.x;
    const int lane = tid & 63;
    const int m    = lane & 15;
    const int quad = lane >> 4;
    const int gw   = blockIdx.x * 4 + (tid >> 6);

    bf16x8 a[4][4];                         // 4 col-tiles x 4 k-chunks, 64 VGPRs
    #pragma unroll
    for (int ct = 0; ct < 4; ++ct)
        #pragma unroll
        for (int kc = 0; kc < 4; ++kc)
            #pragma unroll
            for (int j = 0; j < 8; ++j)
                a[ct][kc][j] = f2bf_s(W2[(size_t)(kc * 32 + quad * 8 + j) * OUT_DIM + ct * 16 + m]);

    float4 b1v[8];                          // bias slice for this lane's k positions
    #pragma unroll
    for (int kc = 0; kc < 4; ++kc) {
        b1v[kc * 2]     = *(const float4*)(b1 + kc * 32 + quad * 8);
        b1v[kc * 2 + 1] = *(const float4*)(b1 + kc * 32 + quad * 8 + 4);
    }

    for (int t = gw; t < NT; t += NW) {
        const int n0 = t * 16;
        int node = n0 + m; if (node >= N) node = N - 1;
        const ushort_t* ar = agg + (size_t)node * HID_DIM + quad * 8;
        f32x4 acc[4];
        #pragma unroll
        for (int ct = 0; ct < 4; ++ct) acc[ct] = (f32x4){0.f, 0.f, 0.f, 0.f};
        #pragma unroll
        for (int kc = 0; kc < 4; ++kc) {
            const ushort4_t r0 = *(const ushort4_t*)(ar + kc * 32);
            const ushort4_t r1 = *(const ushort4_t*)(ar + kc * 32 + 4);
            const float4 ba = b1v[kc * 2], bb = b1v[kc * 2 + 1];
            bf16x8 b;
            b[0] = f2bf_s(fmaxf(bf2f(r0.x) + ba.x, 0.f));
            b[1] = f2bf_s(fmaxf(bf2f(r0.y) + ba.y, 0.f));
            b[2] = f2bf_s(fmaxf(bf2f(r0.z) + ba.z, 0.f));
            b[3] = f2bf_s(fmaxf(bf2f(r0.w) + ba.w, 0.f));
            b[4] = f2bf_s(fmaxf(bf2f(r1.x) + bb.x, 0.f));
            b[5] = f2bf_s(fmaxf(bf2f(r1.y) + bb.y, 0.f));
            b[6] = f2bf_s(fmaxf(bf2f(r1.z) + bb.z, 0.f));
            b[7] = f2bf_s(fmaxf(bf2f(r1.w) + bb.w, 0.f));
            #pragma unroll
            for (int ct = 0; ct < 4; ++ct)
                acc[ct] = __builtin_amdgcn_mfma_f32_16x16x32_bf16(a[ct][kc], b, acc[ct], 0, 0, 0);
        }
        if (n0 + m < N) {
            unsigned int* o = h2 + (size_t)(n0 + m) * (OUT_DIM / 2) + quad * 2;
            #pragma unroll
            for (int ct = 0; ct < 4; ++ct) {
                uint2 pv;
                pv.x = pack2(acc[ct][0], acc[ct][1]);
                pv.y = pack2(acc[ct][2], acc[ct][3]);
                *(uint2*)(o + ct * 8) = pv;
            }
        }
    }
}

// ---------------- gather aggregation, bf16 messages, padded packed records ----------------
// Rows padded to multiples of 4 records; pad records are {0,0.0f} -> no-op.
template<int D, bool BF16_OUT>
__global__ void gather_bf16(const ushort_t* __restrict__ h, const int2* __restrict__ pack,
                            const int* __restrict__ row_start, const int* __restrict__ cnt,
                            const float* __restrict__ dinv, const float* __restrict__ bias,
                            int N, void* __restrict__ outv) {
    const int TPN = D / 4;
    const int NPB = 256 / TPN;
    const int t = threadIdx.x;
    const int node = blockIdx.x * NPB + t / TPN;
    if (node >= N) return;
    const int f = (t & (TPN - 1)) * 4;
    const float dd = dinv[node];

    const ushort4_t self = *(const ushort4_t*)(h + (size_t)node * D + f);
    const float sn = dd * dd;
    float4 acc;
    acc.x = bf2f(self.x) * sn; acc.y = bf2f(self.y) * sn;
    acc.z = bf2f(self.z) * sn; acc.w = bf2f(self.w) * sn;
    if (bias) {
        const float4 b = *(const float4*)(bias + f);
        acc.x += b.x; acc.y += b.y; acc.z += b.z; acc.w += b.w;
    }

    const int2* pk = pack + row_start[node];       // 16B-aligned (start % 4 == 0)
    const int cpad = (cnt[node] + 3) & ~3;
    for (int e = 0; e < cpad; e += 4) {
        const int4 a = *(const int4*)(pk + e);
        const int4 b = *(const int4*)(pk + e + 2);
        {
            const ushort4_t v = *(const ushort4_t*)(h + (size_t)a.x * D + f);
            const float n = __int_as_float(a.y);
            acc.x += bf2f(v.x) * n; acc.y += bf2f(v.y) * n;
            acc.z += bf2f(v.z) * n; acc.w += bf2f(v.w) * n;
        }
        {
            const ushort4_t v = *(const ushort4_t*)(h + (size_t)a.z * D + f);
            const float n = __int_as_float(a.w);
            acc.x += bf2f(v.x) * n; acc.y += bf2f(v.y) * n;
            acc.z += bf2f(v.z) * n; acc.w += bf2f(v.w) * n;
        }
        {
            const ushort4_t v = *(const ushort4_t*)(h + (size_t)b.x * D + f);
            const float n = __int_as_float(b.y);
            acc.x += bf2f(v.x) * n; acc.y += bf2f(v.y) * n;
            acc.z += bf2f(v.z) * n; acc.w += bf2f(v.w) * n;
        }
        {
            const ushort4_t v = *(const ushort4_t*)(h + (size_t)b.z * D + f);
            const float n = __int_as_float(b.w);
            acc.x += bf2f(v.x) * n; acc.y += bf2f(v.y) * n;
            acc.z += bf2f(v.z) * n; acc.w += bf2f(v.w) * n;
        }
    }
    if (BF16_OUT) {
        unsigned int* out = (unsigned int*)outv;
        uint2 pv;
        pv.x = pack2(acc.x, acc.y);
        pv.y = pack2(acc.z, acc.w);
        *(uint2*)(out + ((size_t)node * D + f) / 2) = pv;
    } else {
        float* out = (float*)outv;
        *(float4*)(out + (size_t)node * D + f) = acc;
    }
}

extern "C" void kernel_launch(void* const* d_in, const int* in_sizes, int n_in,
                              void* d_out, int out_size, void* d_ws, size_t ws_size,
                              hipStream_t stream) {
    const float* x   = (const float*)d_in[0];
    const int*   ei  = (const int*)  d_in[1];
    const float* W1  = (const float*)d_in[2];
    const float* b1  = (const float*)d_in[3];
    const float* W2  = (const float*)d_in[4];
    const float* b2  = (const float*)d_in[5];
    float* out = (float*)d_out;

    const int N = in_sizes[0] / IN_DIM;     // 100000
    const int E = in_sizes[1] / 2;          // 1600000
    const int* src = ei;                    // edge_index[0]
    const int* dst = ei + E;                // edge_index[1]

    // workspace layout (4B units):
    // dinv[N] | cnt[N] | row_start[N] | bsum[1024] | align | pack[E+4N] int2
    // | h1[N*64] u32 (bf16 h1, reused as h2) | agg1[N*64] u32 (bf16; rank aliases it)
    const int PACK_CAP = E + 4 * N;
    float* dinv      = (float*)d_ws;
    int*   cnt       = (int*)(dinv + N);
    int*   row_start = cnt + N;
    int*   bsum      = row_start + N;
    size_t off       = (size_t)(3 * N + 1024);
    off = (off + 3) & ~(size_t)3;           // 16B-align pack
    int2*  pack      = (int2*)((int*)d_ws + off);
    unsigned int* h1 = (unsigned int*)(pack + PACK_CAP);
    unsigned int* agg1 = h1 + (size_t)N * (HID_DIM / 2);
    int*   rank      = (int*)agg1;          // alive only until fill_pack (E <= N*64)
    unsigned int* h2 = h1;                  // reuse after gather128

    const int B = 256;
    const int S = (N + 2047) / 2048;        // scan blocks
    const int NT = (N + 15) / 16;           // 16-node MFMA tiles

    // 1) CSR build + dinv
    hipMemsetAsync(cnt, 0, (size_t)N * sizeof(int), stream);
    hipMemsetAsync(pack, 0, (size_t)PACK_CAP * sizeof(int2), stream);
    count_rank<<<(E + B - 1) / B, B, 0, stream>>>(dst, E, cnt, rank);
    make_dinv<<<(N + B - 1) / B, B, 0, stream>>>(cnt, dinv, N);
    scan_partial<<<S, 256, 0, stream>>>(cnt, bsum, N);
    scan_partials<<<1, 64, 0, stream>>>(bsum, S);
    scan_write<<<S, 256, 0, stream>>>(cnt, bsum, row_start, N);
    fill_pack<<<(E + B - 1) / B, B, 0, stream>>>(src, dst, rank, row_start, dinv, E, pack);

    // 2) h1 = x @ W1  (bf16 out, MFMA)
    gemm1_mfma<<<512, 256, 0, stream>>>(x, W1, h1, N, NT, 512 * 4);

    // 3) agg1 = gather(h1)  (bf16 out; overwrites rank)
    gather_bf16<HID_DIM, true><<<(N + 7) / 8, 256, 0, stream>>>(
        (const ushort_t*)h1, pack, row_start, cnt, dinv, nullptr, N, (void*)agg1);

    // 4) h2 = relu(agg1 + b1) @ W2  (bf16 out, MFMA)
    gemm2_mfma<<<768, 256, 0, stream>>>(
        (const ushort_t*)agg1, b1, W2, h2, N, NT, 768 * 4);

    // 5) out = b2 + gather(h2)  (f32 out)
    gather_bf16<OUT_DIM, false><<<(N + 15) / 16, 256, 0, stream>>>(
        (const ushort_t*)h2, pack, row_start, cnt, dinv, b2, N, (void*)out);
}